// Round 1
// baseline (760.829 us; speedup 1.0000x reference)
//
#include <hip/hip_runtime.h>

// TensorProductExpansion, N=100000, MUL=128.
// Factored form: fold w_ss/w_sv/w_vs/w_vv and 1/sqrt(fan) into 4 128x128
// weight matrices (prep kernel), then per sample:
//   out0          = s2 * (s1 @ W0a) + (v1.v2) @ W0b
//   out1[:,w,m]   = v2[m] * (s1 @ W1a) + s2 * (v1_m @ W1b)
// => 6 GEMMs of N x 128 x 128 = 19.7 GFLOP (f32 VALU; no f32 MFMA on CDNA4).

#define TS 16       // samples per block
#define BK 8        // K-slice of weight tile staged per barrier
#define THREADS 256

static constexpr float INV_SQRT3   = 0.57735026918962576451f;
static constexpr float INV_SQRT_FAN = 0.0625f;   // 1/sqrt(2*128) = 1/16

// Build wprep[k][0:512] = [W0a | W0b | W1a | W1b] row k (k = 0..127), k-major
// so the main kernel's staging loads are perfectly coalesced.
__global__ __launch_bounds__(256)
void tpe_prep(const float* __restrict__ w_ss, const float* __restrict__ w_sv,
              const float* __restrict__ w_vs, const float* __restrict__ w_vv,
              const float* __restrict__ W0, const float* __restrict__ W1,
              float* __restrict__ wprep) {
  int e = blockIdx.x * 256 + threadIdx.x;   // 0..65535
  int k = e >> 9;          // 0..127
  int c = e & 511;
  int mat = c >> 7;        // 0..3
  int w = c & 127;
  float val;
  if (mat == 0)      val = w_ss[k] * W0[k * 128 + w];
  else if (mat == 1) val = w_vv[k] * INV_SQRT3 * W0[(128 + k) * 128 + w];
  else if (mat == 2) val = w_sv[k] * W1[k * 128 + w];
  else               val = w_vs[k] * W1[(128 + k) * 128 + w];
  wprep[e] = val * INV_SQRT_FAN;
}

__global__ __launch_bounds__(THREADS, 2)
void tpe_main(const float* __restrict__ left, const float* __restrict__ right,
              const float* __restrict__ wprep, float* __restrict__ out,
              int n_total) {
  // X planes, K-major: 0 = s1, 1 = vv (= v1.v2), 2..4 = v1_m.  40 KB
  __shared__ float xs[5][128][TS];
  __shared__ float wt[BK][512];     // 16 KB: [W0a|W0b|W1a|W1b] slice
  __shared__ float rt[TS][4];       // right tile (s2, v2[3])

  const int tid = threadIdx.x;
  const int n0  = blockIdx.x * TS;

  // ---- stage right tile ----
  if (tid < TS * 4) {
    int s = tid >> 2, q = tid & 3;
    float v = 0.f;
    if (n0 + s < n_total) v = right[(size_t)(n0 + s) * 4 + q];
    rt[s][q] = v;
  }

  // ---- stage left tile -> transposed K-major planes ----
  // 16 samples x 512 f32 = 2048 float4, 8 per thread, coalesced loads.
  #pragma unroll
  for (int i = 0; i < 8; ++i) {
    int e  = i * THREADS + tid;
    int s  = e >> 7;            // sample within tile
    int c4 = e & 127;           // float4 index within row
    int j  = c4 * 4;            // f32 column
    float4 v = make_float4(0.f, 0.f, 0.f, 0.f);
    if (n0 + s < n_total)
      v = reinterpret_cast<const float4*>(left + (size_t)(n0 + s) * 512)[c4];
    float vals[4] = {v.x, v.y, v.z, v.w};
    if (j < 128) {
      #pragma unroll
      for (int q = 0; q < 4; ++q) xs[0][j + q][s] = vals[q];
    } else {
      #pragma unroll
      for (int q = 0; q < 4; ++q) {
        int jj = j + q - 128;          // u*3 + m
        int u  = jj / 3;               // magic-mul
        int m  = jj - u * 3;
        xs[2 + m][u][s] = vals[q];
      }
    }
  }
  __syncthreads();

  // ---- build vv plane: vv[k][s] = sum_m v1_m[k][s] * v2[s][m] ----
  #pragma unroll
  for (int i = 0; i < 8; ++i) {
    int e = i * THREADS + tid;
    int k = e >> 4, s = e & 15;
    xs[1][k][s] = xs[2][k][s] * rt[s][1] + xs[3][k][s] * rt[s][2]
                + xs[4][k][s] * rt[s][3];
  }
  __syncthreads();

  // ---- main GEMM loop ----
  const int colg = tid & 31;      // 32 column groups * 4 cols = 128
  const int row  = tid >> 5;      // 8 rows * 2 samples = 16
  const int c0   = colg * 4;
  const int s0   = row * 2;

  float acc[6][2][4];             // {Y0, Yv, Ya, B0, B1, B2}[sample][col]
  #pragma unroll
  for (int a = 0; a < 6; ++a)
    #pragma unroll
    for (int si = 0; si < 2; ++si)
      #pragma unroll
      for (int ci = 0; ci < 4; ++ci) acc[a][si][ci] = 0.f;

  for (int kt = 0; kt < 128; kt += BK) {
    // stage weight slice wt[BK][512] (coalesced float4, L2-resident source)
    #pragma unroll
    for (int i = 0; i < 4; ++i) {
      int e  = i * THREADS + tid;
      int kk = e >> 7, c4 = e & 127;
      reinterpret_cast<float4*>(&wt[kk][0])[c4] =
          reinterpret_cast<const float4*>(wprep + (size_t)(kt + kk) * 512)[c4];
    }
    __syncthreads();

    #pragma unroll
    for (int kk = 0; kk < BK; ++kk) {
      const int k = kt + kk;
      float xs1[2], xvv[2], xv0[2], xv1[2], xv2[2];
      { float2 t = *reinterpret_cast<const float2*>(&xs[0][k][s0]); xs1[0]=t.x; xs1[1]=t.y; }
      { float2 t = *reinterpret_cast<const float2*>(&xs[1][k][s0]); xvv[0]=t.x; xvv[1]=t.y; }
      { float2 t = *reinterpret_cast<const float2*>(&xs[2][k][s0]); xv0[0]=t.x; xv0[1]=t.y; }
      { float2 t = *reinterpret_cast<const float2*>(&xs[3][k][s0]); xv1[0]=t.x; xv1[1]=t.y; }
      { float2 t = *reinterpret_cast<const float2*>(&xs[4][k][s0]); xv2[0]=t.x; xv2[1]=t.y; }
      float wa[4], wb[4], wc_[4], wd[4];
      { float4 f = *reinterpret_cast<const float4*>(&wt[kk][c0      ]); wa[0]=f.x; wa[1]=f.y; wa[2]=f.z; wa[3]=f.w; }
      { float4 f = *reinterpret_cast<const float4*>(&wt[kk][c0 + 128]); wb[0]=f.x; wb[1]=f.y; wb[2]=f.z; wb[3]=f.w; }
      { float4 f = *reinterpret_cast<const float4*>(&wt[kk][c0 + 256]); wc_[0]=f.x; wc_[1]=f.y; wc_[2]=f.z; wc_[3]=f.w; }
      { float4 f = *reinterpret_cast<const float4*>(&wt[kk][c0 + 384]); wd[0]=f.x; wd[1]=f.y; wd[2]=f.z; wd[3]=f.w; }
      #pragma unroll
      for (int si = 0; si < 2; ++si) {
        #pragma unroll
        for (int ci = 0; ci < 4; ++ci) {
          acc[0][si][ci] = fmaf(xs1[si], wa[ci],  acc[0][si][ci]);  // Y0
          acc[1][si][ci] = fmaf(xvv[si], wb[ci],  acc[1][si][ci]);  // Yv
          acc[2][si][ci] = fmaf(xs1[si], wc_[ci], acc[2][si][ci]);  // Ya
          acc[3][si][ci] = fmaf(xv0[si], wd[ci],  acc[3][si][ci]);  // B0
          acc[4][si][ci] = fmaf(xv1[si], wd[ci],  acc[4][si][ci]);  // B1
          acc[5][si][ci] = fmaf(xv2[si], wd[ci],  acc[5][si][ci]);  // B2
        }
      }
    }
    __syncthreads();
  }

  // ---- epilogue: combine + store ----
  #pragma unroll
  for (int si = 0; si < 2; ++si) {
    int n = n0 + s0 + si;
    if (n < n_total) {
      float s2v = rt[s0 + si][0];
      float v2a = rt[s0 + si][1], v2b = rt[s0 + si][2], v2c = rt[s0 + si][3];
      float* orow = out + (size_t)n * 512;
      float4 o0;
      o0.x = fmaf(s2v, acc[0][si][0], acc[1][si][0]);
      o0.y = fmaf(s2v, acc[0][si][1], acc[1][si][1]);
      o0.z = fmaf(s2v, acc[0][si][2], acc[1][si][2]);
      o0.w = fmaf(s2v, acc[0][si][3], acc[1][si][3]);
      *reinterpret_cast<float4*>(orow + c0) = o0;
      float o1[12];
      #pragma unroll
      for (int ci = 0; ci < 4; ++ci) {
        o1[ci * 3 + 0] = fmaf(v2a, acc[2][si][ci], s2v * acc[3][si][ci]);
        o1[ci * 3 + 1] = fmaf(v2b, acc[2][si][ci], s2v * acc[4][si][ci]);
        o1[ci * 3 + 2] = fmaf(v2c, acc[2][si][ci], s2v * acc[5][si][ci]);
      }
      float* p1 = orow + 128 + 3 * c0;   // byte offset 512+48*colg: 16B aligned
      #pragma unroll
      for (int q = 0; q < 3; ++q)
        *reinterpret_cast<float4*>(p1 + 4 * q) =
            make_float4(o1[4 * q], o1[4 * q + 1], o1[4 * q + 2], o1[4 * q + 3]);
    }
  }
}

extern "C" void kernel_launch(void* const* d_in, const int* in_sizes, int n_in,
                              void* d_out, int out_size, void* d_ws, size_t ws_size,
                              hipStream_t stream) {
  const float* left  = (const float*)d_in[0];
  const float* right = (const float*)d_in[1];
  const float* w_ss  = (const float*)d_in[2];
  const float* w_sv  = (const float*)d_in[3];
  const float* w_vs  = (const float*)d_in[4];
  const float* w_vv  = (const float*)d_in[5];
  const float* W0    = (const float*)d_in[6];
  const float* W1    = (const float*)d_in[7];
  float* out   = (float*)d_out;
  float* wprep = (float*)d_ws;            // 128*512 f32 = 256 KB scratch

  int n = in_sizes[0] / 512;              // 100000

  tpe_prep<<<256, 256, 0, stream>>>(w_ss, w_sv, w_vs, w_vv, W0, W1, wprep);
  tpe_main<<<(n + TS - 1) / TS, THREADS, 0, stream>>>(left, right, wprep, out, n);
}